// Round 5
// baseline (407.253 us; speedup 1.0000x reference)
//
#include <hip/hip_runtime.h>
#include <cstdint>
#include <cstddef>

#define T_STEPS 50
#define B_SZ    1024
#define N_INP   784
#define H_SZ    256
#define L_SZ    10
#define M_TOT   (T_STEPS * B_SZ)   // 51200
#define NK0     26                 // K padded to 26*32 = 832
#define NSLICE  5                  // 5 balanced base-256 digits of rint(Wi*2^40): exact (|Wi|<0.5)

typedef int v4i  __attribute__((ext_vector_type(4)));
typedef int v16i __attribute__((ext_vector_type(16)));

// ---------------------------------------------------------------------------
// Phase 0a: transpose Wr[h][k] (256x256, fp32) -> WrTz[k][h]; block (0,0) also
// zeroes dummy row 256 (global gather pad target).
// ---------------------------------------------------------------------------
__global__ __launch_bounds__(256) void transpose_wr(const float* __restrict__ Wr,
                                                    float* __restrict__ WrTz) {
    __shared__ float tile[32][33];
    int bx = blockIdx.x * 32, by = blockIdx.y * 32;
    int tx = threadIdx.x % 32, ty = threadIdx.x / 32;   // 32 x 8
    #pragma unroll
    for (int j = 0; j < 32; j += 8)
        tile[ty + j][tx] = Wr[(size_t)(by + ty + j) * H_SZ + bx + tx];
    if (blockIdx.x == 0 && blockIdx.y == 0)
        WrTz[(size_t)256 * H_SZ + threadIdx.x] = 0.0f;   // dummy zero row
    __syncthreads();
    #pragma unroll
    for (int j = 0; j < 32; j += 8)
        WrTz[(size_t)(bx + ty + j) * H_SZ + by + tx] = tile[tx][ty + j];
}

// ---------------------------------------------------------------------------
// Phase 0b: Wi -> 5 balanced int8 digits of rint(Wi*2^40), fragment-linear.
// (R5/R6-verified exact, absmax 0.)
// ---------------------------------------------------------------------------
__global__ __launch_bounds__(128) void prep_packed(const float* __restrict__ Wi,
                                                   uint8_t* __restrict__ SBp) {
    const int nt   = blockIdx.x;
    const int k0   = blockIdx.y * 2 + (threadIdx.x >> 6);
    const int lane = threadIdx.x & 63;
    const int h    = nt * 32 + (lane & 31);
    const int g    = k0 * 2 + (lane >> 5);     // 16-float group index

    int wd[NSLICE][4] = {};
    #pragma unroll
    for (int u = 0; u < 16; ++u) {
        double wv = 0.0;
        if (g < 49) wv = (double)Wi[(size_t)h * N_INP + g * 16 + u];
        double r = rint(wv * 0x1p40);
        #pragma unroll
        for (int j = 0; j < NSLICE - 1; ++j) {
            double q  = floor((r + 128.0) * 0.00390625);
            double dj = r - 256.0 * q;                     // in [-128,127]
            wd[j][u >> 2] |= ((int)dj & 0xFF) << ((u & 3) * 8);
            r = q;
        }
        wd[NSLICE - 1][u >> 2] |= ((int)r & 0xFF) << ((u & 3) * 8);
    }
    uint8_t* base = SBp + ((size_t)(nt * NK0 + k0) * NSLICE) * 1024 + lane * 16;
    #pragma unroll
    for (int j = 0; j < NSLICE; ++j)
        *(v4i*)(base + (size_t)j * 1024) = (v4i){wd[j][0], wd[j][1], wd[j][2], wd[j][3]};
}

// ---------------------------------------------------------------------------
// Phase 0c: pack X (binary fp32) -> fragment-linear int8 (R6-verified).
// ---------------------------------------------------------------------------
__global__ __launch_bounds__(256) void pack_x(const float* __restrict__ X,
                                              uint8_t* __restrict__ Ap) {
    const int mt  = blockIdx.x;       // 1600
    const int tid = threadIdx.x;
    #pragma unroll
    for (int i = 0; i < 7; ++i) {
        int s = tid + i * 256;
        if (s < NK0 * 64) {
            int k0 = s >> 6, lane = s & 63;
            int m = mt * 32 + (lane & 31);
            int g = k0 * 2 + (lane >> 5);
            unsigned int bw[4] = {0u, 0u, 0u, 0u};
            if (g < 49) {
                const float* src = X + (size_t)m * N_INP + g * 16;
                #pragma unroll
                for (int q = 0; q < 4; ++q) {
                    float4 f = *(const float4*)(src + q * 4);
                    bw[q] = (f.x != 0.f ? 1u : 0u) | (f.y != 0.f ? 0x100u : 0u)
                          | (f.z != 0.f ? 0x10000u : 0u) | (f.w != 0.f ? 0x1000000u : 0u);
                }
            }
            *(v4i*)(Ap + ((size_t)(mt * NK0 + k0)) * 1024 + lane * 16) =
                (v4i){(int)bw[0], (int)bw[1], (int)bw[2], (int)bw[3]};
        }
    }
}

// ---------------------------------------------------------------------------
// Phase 1 v2 (R4-verified, kept): cur = X @ Wi.T exactly via 5 int8-digit
// MFMAs; B staged via global_load_lds width=16, 4-k0 double-buffered stages.
// ---------------------------------------------------------------------------
typedef __attribute__((address_space(1))) uint32_t glds_g;
typedef __attribute__((address_space(3))) uint32_t glds_l;

#define STAGE_B(dstbuf, srcp, NI)                                               \
    {                                                                           \
        _Pragma("unroll")                                                       \
        for (int j_ = 0; j_ < (NI); ++j_) {                                     \
            int s_ = j_ * 256 + tid;                                            \
            __builtin_amdgcn_global_load_lds(                                   \
                (glds_g*)((srcp) + (size_t)s_ * 16),                            \
                (glds_l*)((dstbuf) + (size_t)s_ * 16), 16, 0, 0);               \
        }                                                                       \
    }

#define MFMA_STAGE(CB, A0, A1, NK)                                              \
    _Pragma("unroll")                                                           \
    for (int dk = 0; dk < (NK); ++dk) {                                         \
        _Pragma("unroll")                                                       \
        for (int j = 0; j < NSLICE; ++j) {                                      \
            v4i b = *(const v4i*)(Bs[CB] + (dk * NSLICE + j) * 1024 + lane * 16); \
            acc0[j] = __builtin_amdgcn_mfma_i32_32x32x32_i8(A0[dk], b, acc0[j], 0, 0, 0); \
            acc1[j] = __builtin_amdgcn_mfma_i32_32x32x32_i8(A1[dk], b, acc1[j], 0, 0, 0); \
        }                                                                       \
    }

__global__ __launch_bounds__(256) void gemm_i8s(const uint8_t* __restrict__ Ap,
                                                const uint8_t* __restrict__ SBp,
                                                double* __restrict__ cur) {
    __shared__ __align__(16) uint8_t Bs[2][4 * NSLICE * 1024];   // 2 x 20 KB

    const int tid   = threadIdx.x;
    const int wave  = tid >> 6;
    const int lane  = tid & 63;
    const int ghalf = lane >> 5;
    const int nt    = blockIdx.y;
    const int mt0   = (blockIdx.x * 4 + wave) * 2;     // wave owns mt0, mt0+1
    const int mt1   = mt0 + 1;

    const uint8_t* ap0 = Ap + (size_t)mt0 * NK0 * 1024 + lane * 16;
    const uint8_t* ap1 = Ap + (size_t)mt1 * NK0 * 1024 + lane * 16;
    const uint8_t* bbase = SBp + ((size_t)nt * NK0 * NSLICE) * 1024;

    v4i a0[4], a1[4], n0[4], n1[4];

    // prologue: stage stage-0 (k0 0..3), prefetch its A fragments
    STAGE_B(Bs[0], bbase, 5);
    #pragma unroll
    for (int dk = 0; dk < 4; ++dk) {
        a0[dk] = *(const v4i*)(ap0 + (size_t)dk * 1024);
        a1[dk] = *(const v4i*)(ap1 + (size_t)dk * 1024);
    }
    __syncthreads();                       // vmcnt(0): stage-0 resident

    v16i acc0[NSLICE] = {};
    v16i acc1[NSLICE] = {};

    for (int s = 0; s < 6; ++s) {
        const int cb = s & 1;
        if (s < 5) {                       // full next stage: 4 k0, 20 KB
            STAGE_B(Bs[cb ^ 1], bbase + (size_t)(s + 1) * 20480, 5);
            #pragma unroll
            for (int dk = 0; dk < 4; ++dk) {
                n0[dk] = *(const v4i*)(ap0 + (size_t)((s + 1) * 4 + dk) * 1024);
                n1[dk] = *(const v4i*)(ap1 + (size_t)((s + 1) * 4 + dk) * 1024);
            }
        } else {                           // tail stage: k0 24..25 (+pad)
            STAGE_B(Bs[cb ^ 1], bbase + (size_t)6 * 20480, 3);
            #pragma unroll
            for (int dk = 0; dk < 2; ++dk) {
                n0[dk] = *(const v4i*)(ap0 + (size_t)(24 + dk) * 1024);
                n1[dk] = *(const v4i*)(ap1 + (size_t)(24 + dk) * 1024);
            }
        }
        MFMA_STAGE(cb, a0, a1, 4);
        __syncthreads();                   // next stage resident; cb free to reuse
        #pragma unroll
        for (int dk = 0; dk < 4; ++dk) { a0[dk] = n0[dk]; a1[dk] = n1[dk]; }
    }
    MFMA_STAGE(0, a0, a1, 2);              // tail: k0 24..25 in Bs[0]

    // recombine digits (exact integer Horner in fp64) and store both m-tiles
    const int h = nt * 32 + (lane & 31);
    #pragma unroll
    for (int r = 0; r < 16; ++r) {
        int mloc = (r & 3) + 8 * (r >> 2) + 4 * ghalf;
        double s0 = (double)acc0[4][r];
        s0 = s0 * 256.0 + (double)acc0[3][r];
        s0 = s0 * 256.0 + (double)acc0[2][r];
        s0 = s0 * 256.0 + (double)acc0[1][r];
        s0 = s0 * 256.0 + (double)acc0[0][r];
        cur[(size_t)(mt0 * 32 + mloc) * H_SZ + h] = s0 * 0x1p-40;
        double s1 = (double)acc1[4][r];
        s1 = s1 * 256.0 + (double)acc1[3][r];
        s1 = s1 * 256.0 + (double)acc1[2][r];
        s1 = s1 * 256.0 + (double)acc1[1][r];
        s1 = s1 * 256.0 + (double)acc1[0][r];
        cur[(size_t)(mt1 * 32 + mloc) * H_SZ + h] = s1 * 0x1p-40;
    }
}

// ---------------------------------------------------------------------------
// Phase 2 v5: 50 LIF steps fp64, wave-per-batch-element, ZERO barriers in the
// time loop. Block = 256 thr = 4 waves = 4 b's (256 blocks, 1/CU, 4 b/CU —
// full 256-CU coverage preserved). Lane L owns neurons h = 4L..4L+3, so all
// cross-neuron communication is __ballot (wave-synchronous, race-free).
// Hybrid gather: Wr rows 0..143 staged in LDS (+zero row 144) -> ds_read_b128
// float4 per lane; rows 144..255 from global (zero row 256) -> float4 loads,
// 2-deep pipelined (1 wave/SIMD must self-hide latency). Per-wave PRIVATE
// lists built each step from the previous step's ballots (kept in registers):
// build->gather same step, same wave, program-order — no parity, no sync.
// Pads (16 low / 24 high) cover all speculative prefetches with exact +0.0.
// fp64 value set identical; reduction regrouped (v1..v4 reorder precedent).
// ---------------------------------------------------------------------------
#define ACC8(A0,A1,A2,A3,A4,A5,A6,A7)                          \
    r0 += (double)A0.x + (double)A1.x;                         \
    r1 += (double)A0.y + (double)A1.y;                         \
    r2 += (double)A0.z + (double)A1.z;                         \
    r3 += (double)A0.w + (double)A1.w;                         \
    r0 += (double)A2.x + (double)A3.x;                         \
    r1 += (double)A2.y + (double)A3.y;                         \
    r2 += (double)A2.z + (double)A3.z;                         \
    r3 += (double)A2.w + (double)A3.w;                         \
    r0 += (double)A4.x + (double)A5.x;                         \
    r1 += (double)A4.y + (double)A5.y;                         \
    r2 += (double)A4.z + (double)A5.z;                         \
    r3 += (double)A4.w + (double)A5.w;                         \
    r0 += (double)A6.x + (double)A7.x;                         \
    r1 += (double)A6.y + (double)A7.y;                         \
    r2 += (double)A6.z + (double)A7.z;                         \
    r3 += (double)A6.w + (double)A7.w;

__global__ __launch_bounds__(256, 1) void snn_scan(const double* __restrict__ cur,
                                                   const float* __restrict__ WrTz,
                                                   const float* __restrict__ Wout,
                                                   const float* __restrict__ bout,
                                                   float* __restrict__ out) {
    const int tid  = threadIdx.x;
    const int wv   = tid >> 6;          // wave = batch element within block
    const int lane = tid & 63;
    const int b    = blockIdx.x * 4 + wv;

    __shared__ __align__(16) float WrL[145 * 256];      // 148,480 B (rows 0..143 + zero row)
    __shared__ __align__(16) int   listLo[4][160];      //   2,560 B
    __shared__ __align__(16) int   listHi[4][136];      //   2,176 B
    __shared__ float cntW[4][256];                      //   4,096 B  (157,312 total)

    // cooperative stage of rows 0..143 (+ zeroed row 144)
    for (int s = tid; s < 145 * 64; s += 256) {
        float4 val = (s < 144 * 64) ? ((const float4*)WrTz)[s]
                                    : make_float4(0.f, 0.f, 0.f, 0.f);
        ((float4*)WrL)[s] = val;
    }
    __syncthreads();                    // the ONLY block-wide barrier

    double vv[4]   = {0.0, 0.0, 0.0, 0.0};
    double syn[4]  = {0.0, 0.0, 0.0, 0.0};
    double inpc[4];
    int    cnt[4]  = {0, 0, 0, 0};
    unsigned long long mOld[4] = {0ull, 0ull, 0ull, 0ull};

    const double* curb = cur + (size_t)b * H_SZ + 4 * lane;
    {
        double2 a0 = *(const double2*)(curb);
        double2 a1 = *(const double2*)(curb + 2);
        inpc[0] = a0.x; inpc[1] = a0.y; inpc[2] = a1.x; inpc[3] = a1.y;
    }

    const char*    wrb    = (const char*)WrTz;
    const int      lane4  = lane * 4;                    // float offset in WrL row
    const uint32_t lane16 = (uint32_t)(lane * 16);       // byte offset in global row
    const unsigned long long lm = (1ull << lane) - 1ull;
    const int rb = 4 * lane;

    int* lo = listLo[wv];
    int* hi = listHi[wv];

    for (int t = 0; t < T_STEPS; ++t) {
        // LIF dynamics (reference op order, fp64) + new ballots
        double idc[4]; bool z[4];
        #pragma unroll
        for (int j = 0; j < 4; ++j) {
            double vd = vv[j] + 0.05 * ((0.0 - vv[j]) + syn[j]);
            idc[j] = 0.9 * syn[j];
            z[j]   = vd > 0.5;
            vv[j]  = z[j] ? 0.0 : vd;
            cnt[j] += z[j] ? 1 : 0;
        }
        unsigned long long mNew[4];
        #pragma unroll
        for (int j = 0; j < 4; ++j) mNew[j] = __ballot((int)z[j]);

        // prefetch next-step input drive
        int tn = (t < T_STEPS - 1) ? t + 1 : t;
        double2 ina = *(const double2*)(curb + (size_t)tn * (B_SZ * H_SZ));
        double2 inb = *(const double2*)(curb + (size_t)tn * (B_SZ * H_SZ) + 2);

        // build this step's private lists from mOld (spikes of step t-1)
        const unsigned long long LOWM = (1ull << 36) - 1ull;   // lanes whose 4 rows < 144
        int pl[4], bj[4], cL[4], cA[4];
        #pragma unroll
        for (int j = 0; j < 4; ++j) {
            pl[j] = __popcll(mOld[j] & lm);
            bj[j] = (int)((mOld[j] >> lane) & 1ull);
            cL[j] = __popcll(mOld[j] & LOWM);
            cA[j] = __popcll(mOld[j]);
        }
        const int below = pl[0] + pl[1] + pl[2] + pl[3];
        const int nLo   = cL[0] + cL[1] + cL[2] + cL[3];
        const int nHi   = (cA[0] + cA[1] + cA[2] + cA[3]) - nLo;
        if (lane < 36) {                 // all 4 rows in the LDS tier
            int p = below;
            if (bj[0]) lo[p] = (rb + 0) << 8;  p += bj[0];
            if (bj[1]) lo[p] = (rb + 1) << 8;  p += bj[1];
            if (bj[2]) lo[p] = (rb + 2) << 8;  p += bj[2];
            if (bj[3]) lo[p] = (rb + 3) << 8;
        } else {                         // all 4 rows in the global tier
            int p = below - nLo;
            if (bj[0]) hi[p] = (rb + 0) << 10; p += bj[0];
            if (bj[1]) hi[p] = (rb + 1) << 10; p += bj[1];
            if (bj[2]) hi[p] = (rb + 2) << 10; p += bj[2];
            if (bj[3]) hi[p] = (rb + 3) << 10;
        }
        if (lane < 16) lo[nLo + lane] = 144 << 8;     // LDS zero row pads
        if (lane < 24) hi[nHi + lane] = 256 << 10;    // global zero row pads

        // gather
        double r0 = 0.0, r1 = 0.0, r2 = 0.0, r3 = 0.0;
        {
            // pre-issue global batches 0,1 (latency hides under the LDS loop)
            v4i h0 = *(const v4i*)(hi + 0),  h1 = *(const v4i*)(hi + 4);
            float4 GA0 = *(const float4*)(wrb + ((uint32_t)h0.x + lane16));
            float4 GA1 = *(const float4*)(wrb + ((uint32_t)h0.y + lane16));
            float4 GA2 = *(const float4*)(wrb + ((uint32_t)h0.z + lane16));
            float4 GA3 = *(const float4*)(wrb + ((uint32_t)h0.w + lane16));
            float4 GA4 = *(const float4*)(wrb + ((uint32_t)h1.x + lane16));
            float4 GA5 = *(const float4*)(wrb + ((uint32_t)h1.y + lane16));
            float4 GA6 = *(const float4*)(wrb + ((uint32_t)h1.z + lane16));
            float4 GA7 = *(const float4*)(wrb + ((uint32_t)h1.w + lane16));
            v4i h2 = *(const v4i*)(hi + 8),  h3 = *(const v4i*)(hi + 12);
            float4 GB0 = *(const float4*)(wrb + ((uint32_t)h2.x + lane16));
            float4 GB1 = *(const float4*)(wrb + ((uint32_t)h2.y + lane16));
            float4 GB2 = *(const float4*)(wrb + ((uint32_t)h2.z + lane16));
            float4 GB3 = *(const float4*)(wrb + ((uint32_t)h2.w + lane16));
            float4 GB4 = *(const float4*)(wrb + ((uint32_t)h3.x + lane16));
            float4 GB5 = *(const float4*)(wrb + ((uint32_t)h3.y + lane16));
            float4 GB6 = *(const float4*)(wrb + ((uint32_t)h3.z + lane16));
            float4 GB7 = *(const float4*)(wrb + ((uint32_t)h3.w + lane16));

            // LDS loop, 1-deep pipelined
            v4i l0 = *(const v4i*)(lo + 0), l1 = *(const v4i*)(lo + 4);
            float4 LA0 = *(const float4*)(WrL + (l0.x + lane4));
            float4 LA1 = *(const float4*)(WrL + (l0.y + lane4));
            float4 LA2 = *(const float4*)(WrL + (l0.z + lane4));
            float4 LA3 = *(const float4*)(WrL + (l0.w + lane4));
            float4 LA4 = *(const float4*)(WrL + (l1.x + lane4));
            float4 LA5 = *(const float4*)(WrL + (l1.y + lane4));
            float4 LA6 = *(const float4*)(WrL + (l1.z + lane4));
            float4 LA7 = *(const float4*)(WrL + (l1.w + lane4));
            for (int j = 0; j < nLo; j += 8) {
                v4i u0 = *(const v4i*)(lo + j + 8), u1 = *(const v4i*)(lo + j + 12);
                float4 LB0 = *(const float4*)(WrL + (u0.x + lane4));
                float4 LB1 = *(const float4*)(WrL + (u0.y + lane4));
                float4 LB2 = *(const float4*)(WrL + (u0.z + lane4));
                float4 LB3 = *(const float4*)(WrL + (u0.w + lane4));
                float4 LB4 = *(const float4*)(WrL + (u1.x + lane4));
                float4 LB5 = *(const float4*)(WrL + (u1.y + lane4));
                float4 LB6 = *(const float4*)(WrL + (u1.z + lane4));
                float4 LB7 = *(const float4*)(WrL + (u1.w + lane4));
                ACC8(LA0, LA1, LA2, LA3, LA4, LA5, LA6, LA7)
                LA0 = LB0; LA1 = LB1; LA2 = LB2; LA3 = LB3;
                LA4 = LB4; LA5 = LB5; LA6 = LB6; LA7 = LB7;
            }

            // global loop, 2-deep pipelined
            for (int j = 0; j < nHi; j += 8) {
                v4i u0 = *(const v4i*)(hi + j + 16), u1 = *(const v4i*)(hi + j + 20);
                float4 GC0 = *(const float4*)(wrb + ((uint32_t)u0.x + lane16));
                float4 GC1 = *(const float4*)(wrb + ((uint32_t)u0.y + lane16));
                float4 GC2 = *(const float4*)(wrb + ((uint32_t)u0.z + lane16));
                float4 GC3 = *(const float4*)(wrb + ((uint32_t)u0.w + lane16));
                float4 GC4 = *(const float4*)(wrb + ((uint32_t)u1.x + lane16));
                float4 GC5 = *(const float4*)(wrb + ((uint32_t)u1.y + lane16));
                float4 GC6 = *(const float4*)(wrb + ((uint32_t)u1.z + lane16));
                float4 GC7 = *(const float4*)(wrb + ((uint32_t)u1.w + lane16));
                ACC8(GA0, GA1, GA2, GA3, GA4, GA5, GA6, GA7)
                GA0 = GB0; GA1 = GB1; GA2 = GB2; GA3 = GB3;
                GA4 = GB4; GA5 = GB5; GA6 = GB6; GA7 = GB7;
                GB0 = GC0; GB1 = GC1; GB2 = GC2; GB3 = GC3;
                GB4 = GC4; GB5 = GC5; GB6 = GC6; GB7 = GC7;
            }
        }

        // synaptic update (same shape as v2: (i_dec + inp) + R)
        syn[0] = (idc[0] + inpc[0]) + r0;
        syn[1] = (idc[1] + inpc[1]) + r1;
        syn[2] = (idc[2] + inpc[2]) + r2;
        syn[3] = (idc[3] + inpc[3]) + r3;
        inpc[0] = ina.x; inpc[1] = ina.y; inpc[2] = inb.x; inpc[3] = inb.y;
        #pragma unroll
        for (int j = 0; j < 4; ++j) mOld[j] = mNew[j];
    }

    // epilogue (wave-private: ds_write then ds_read within the same wave)
    #pragma unroll
    for (int j = 0; j < 4; ++j) cntW[wv][rb + j] = (float)cnt[j];
    if (lane < L_SZ) {
        double s = 0.0;
        for (int k = 0; k < H_SZ; ++k)
            s += (double)cntW[wv][k] * (double)Wout[(size_t)lane * H_SZ + k];
        s += (double)T_STEPS * (double)bout[lane];
        out[(size_t)b * L_SZ + lane] = (float)(s / (double)T_STEPS);
    }
}

// ---------------------------------------------------------------------------
extern "C" void kernel_launch(void* const* d_in, const int* in_sizes, int n_in,
                              void* d_out, int out_size, void* d_ws, size_t ws_size,
                              hipStream_t stream) {
    const float* x    = (const float*)d_in[0];   // [50,1024,784]
    const float* Wi   = (const float*)d_in[1];   // [256,784]
    const float* Wr   = (const float*)d_in[2];   // [256,256]
    const float* Wout = (const float*)d_in[3];   // [10,256]
    const float* bout = (const float*)d_in[4];   // [10]
    float* out = (float*)d_out;                  // [1024,10]

    // ws layout (~148.8 MB)
    char* ws = (char*)d_ws;
    double*  cur  = (double*)(ws);                       // 104,857,600 B
    float*   WrTz = (float*)(ws + 104857600);            // 257 rows x 256 x 4 = 263,168 B
    uint8_t* SBp  = (uint8_t*)(ws + 105121792);          //   1,064,960 B
    uint8_t* Ap   = (uint8_t*)(ws + 106186752);          //  42,598,400 B

    hipLaunchKernelGGL(transpose_wr, dim3(8, 8), dim3(256), 0, stream, Wr, WrTz);
    hipLaunchKernelGGL(prep_packed, dim3(8, 13), dim3(128), 0, stream, Wi, SBp);
    hipLaunchKernelGGL(pack_x, dim3(M_TOT / 32), dim3(256), 0, stream, x, Ap);
    hipLaunchKernelGGL(gemm_i8s, dim3(M_TOT / 256, 8), dim3(256), 0, stream, Ap, SBp, cur);
    hipLaunchKernelGGL(snn_scan, dim3(B_SZ / 4), dim3(256), 0, stream,
                       cur, WrTz, Wout, bout, out);
}

// Round 6
// 381.869 us; speedup vs baseline: 1.0665x; 1.0665x over previous
//
#include <hip/hip_runtime.h>
#include <cstdint>
#include <cstddef>

#define T_STEPS 50
#define B_SZ    1024
#define N_INP   784
#define H_SZ    256
#define L_SZ    10
#define M_TOT   (T_STEPS * B_SZ)   // 51200
#define NK0     26                 // K padded to 26*32 = 832
#define NSLICE  5                  // 5 balanced base-256 digits of rint(Wi*2^40): exact (|Wi|<0.5)

typedef int v4i  __attribute__((ext_vector_type(4)));
typedef int v16i __attribute__((ext_vector_type(16)));

// ---------------------------------------------------------------------------
// Phase 0a: transpose Wr[h][k] (256x256, fp32) -> WrTz[k][h]; block (0,0) also
// zeroes dummy row 256 (gather pad target).
// ---------------------------------------------------------------------------
__global__ __launch_bounds__(256) void transpose_wr(const float* __restrict__ Wr,
                                                    float* __restrict__ WrTz) {
    __shared__ float tile[32][33];
    int bx = blockIdx.x * 32, by = blockIdx.y * 32;
    int tx = threadIdx.x % 32, ty = threadIdx.x / 32;   // 32 x 8
    #pragma unroll
    for (int j = 0; j < 32; j += 8)
        tile[ty + j][tx] = Wr[(size_t)(by + ty + j) * H_SZ + bx + tx];
    if (blockIdx.x == 0 && blockIdx.y == 0)
        WrTz[(size_t)256 * H_SZ + threadIdx.x] = 0.0f;   // dummy zero row
    __syncthreads();
    #pragma unroll
    for (int j = 0; j < 32; j += 8)
        WrTz[(size_t)(bx + ty + j) * H_SZ + by + tx] = tile[tx][ty + j];
}

// ---------------------------------------------------------------------------
// Phase 0b: Wi -> 5 balanced int8 digits of rint(Wi*2^40), fragment-linear.
// (R5/R6-verified exact, absmax 0.)
// ---------------------------------------------------------------------------
__global__ __launch_bounds__(128) void prep_packed(const float* __restrict__ Wi,
                                                   uint8_t* __restrict__ SBp) {
    const int nt   = blockIdx.x;
    const int k0   = blockIdx.y * 2 + (threadIdx.x >> 6);
    const int lane = threadIdx.x & 63;
    const int h    = nt * 32 + (lane & 31);
    const int g    = k0 * 2 + (lane >> 5);     // 16-float group index

    int wd[NSLICE][4] = {};
    #pragma unroll
    for (int u = 0; u < 16; ++u) {
        double wv = 0.0;
        if (g < 49) wv = (double)Wi[(size_t)h * N_INP + g * 16 + u];
        double r = rint(wv * 0x1p40);
        #pragma unroll
        for (int j = 0; j < NSLICE - 1; ++j) {
            double q  = floor((r + 128.0) * 0.00390625);
            double dj = r - 256.0 * q;                     // in [-128,127]
            wd[j][u >> 2] |= ((int)dj & 0xFF) << ((u & 3) * 8);
            r = q;
        }
        wd[NSLICE - 1][u >> 2] |= ((int)r & 0xFF) << ((u & 3) * 8);
    }
    uint8_t* base = SBp + ((size_t)(nt * NK0 + k0) * NSLICE) * 1024 + lane * 16;
    #pragma unroll
    for (int j = 0; j < NSLICE; ++j)
        *(v4i*)(base + (size_t)j * 1024) = (v4i){wd[j][0], wd[j][1], wd[j][2], wd[j][3]};
}

// ---------------------------------------------------------------------------
// Phase 0c: pack X (binary fp32) -> fragment-linear int8 (R6-verified).
// ---------------------------------------------------------------------------
__global__ __launch_bounds__(256) void pack_x(const float* __restrict__ X,
                                              uint8_t* __restrict__ Ap) {
    const int mt  = blockIdx.x;       // 1600
    const int tid = threadIdx.x;
    #pragma unroll
    for (int i = 0; i < 7; ++i) {
        int s = tid + i * 256;
        if (s < NK0 * 64) {
            int k0 = s >> 6, lane = s & 63;
            int m = mt * 32 + (lane & 31);
            int g = k0 * 2 + (lane >> 5);
            unsigned int bw[4] = {0u, 0u, 0u, 0u};
            if (g < 49) {
                const float* src = X + (size_t)m * N_INP + g * 16;
                #pragma unroll
                for (int q = 0; q < 4; ++q) {
                    float4 f = *(const float4*)(src + q * 4);
                    bw[q] = (f.x != 0.f ? 1u : 0u) | (f.y != 0.f ? 0x100u : 0u)
                          | (f.z != 0.f ? 0x10000u : 0u) | (f.w != 0.f ? 0x1000000u : 0u);
                }
            }
            *(v4i*)(Ap + ((size_t)(mt * NK0 + k0)) * 1024 + lane * 16) =
                (v4i){(int)bw[0], (int)bw[1], (int)bw[2], (int)bw[3]};
        }
    }
}

// ---------------------------------------------------------------------------
// Phase 1 v3: cur = X @ Wi.T exactly via 5 int8-digit MFMAs.
// v2 (R3): B staged via global_load_lds width=16, 4-k0 double-buffered stages.
// v3 (this round): __launch_bounds__(256, 2) forces <=256 VGPR/wave so TWO
// blocks co-reside per CU (2 waves/SIMD): block A's MFMAs cover block B's
// per-stage vmcnt(0) barrier drain and vice versa. Values bit-identical.
// ---------------------------------------------------------------------------
typedef __attribute__((address_space(1))) uint32_t glds_g;
typedef __attribute__((address_space(3))) uint32_t glds_l;

#define STAGE_B(dstbuf, srcp, NI)                                               \
    {                                                                           \
        _Pragma("unroll")                                                       \
        for (int j_ = 0; j_ < (NI); ++j_) {                                     \
            int s_ = j_ * 256 + tid;                                            \
            __builtin_amdgcn_global_load_lds(                                   \
                (glds_g*)((srcp) + (size_t)s_ * 16),                            \
                (glds_l*)((dstbuf) + (size_t)s_ * 16), 16, 0, 0);               \
        }                                                                       \
    }

#define MFMA_STAGE(CB, A0, A1, NK)                                              \
    _Pragma("unroll")                                                           \
    for (int dk = 0; dk < (NK); ++dk) {                                         \
        _Pragma("unroll")                                                       \
        for (int j = 0; j < NSLICE; ++j) {                                      \
            v4i b = *(const v4i*)(Bs[CB] + (dk * NSLICE + j) * 1024 + lane * 16); \
            acc0[j] = __builtin_amdgcn_mfma_i32_32x32x32_i8(A0[dk], b, acc0[j], 0, 0, 0); \
            acc1[j] = __builtin_amdgcn_mfma_i32_32x32x32_i8(A1[dk], b, acc1[j], 0, 0, 0); \
        }                                                                       \
    }

__global__ __launch_bounds__(256, 2) void gemm_i8s(const uint8_t* __restrict__ Ap,
                                                   const uint8_t* __restrict__ SBp,
                                                   double* __restrict__ cur) {
    __shared__ __align__(16) uint8_t Bs[2][4 * NSLICE * 1024];   // 2 x 20 KB

    const int tid   = threadIdx.x;
    const int wave  = tid >> 6;
    const int lane  = tid & 63;
    const int ghalf = lane >> 5;
    const int nt    = blockIdx.y;
    const int mt0   = (blockIdx.x * 4 + wave) * 2;     // wave owns mt0, mt0+1
    const int mt1   = mt0 + 1;

    const uint8_t* ap0 = Ap + (size_t)mt0 * NK0 * 1024 + lane * 16;
    const uint8_t* ap1 = Ap + (size_t)mt1 * NK0 * 1024 + lane * 16;
    const uint8_t* bbase = SBp + ((size_t)nt * NK0 * NSLICE) * 1024;

    v4i a0[4], a1[4], n0[4], n1[4];

    // prologue: stage stage-0 (k0 0..3), prefetch its A fragments
    STAGE_B(Bs[0], bbase, 5);
    #pragma unroll
    for (int dk = 0; dk < 4; ++dk) {
        a0[dk] = *(const v4i*)(ap0 + (size_t)dk * 1024);
        a1[dk] = *(const v4i*)(ap1 + (size_t)dk * 1024);
    }
    __syncthreads();                       // vmcnt(0): stage-0 resident

    v16i acc0[NSLICE] = {};
    v16i acc1[NSLICE] = {};

    for (int s = 0; s < 6; ++s) {
        const int cb = s & 1;
        if (s < 5) {                       // full next stage: 4 k0, 20 KB
            STAGE_B(Bs[cb ^ 1], bbase + (size_t)(s + 1) * 20480, 5);
            #pragma unroll
            for (int dk = 0; dk < 4; ++dk) {
                n0[dk] = *(const v4i*)(ap0 + (size_t)((s + 1) * 4 + dk) * 1024);
                n1[dk] = *(const v4i*)(ap1 + (size_t)((s + 1) * 4 + dk) * 1024);
            }
        } else {                           // tail stage: k0 24..25 (+pad)
            STAGE_B(Bs[cb ^ 1], bbase + (size_t)6 * 20480, 3);
            #pragma unroll
            for (int dk = 0; dk < 2; ++dk) {
                n0[dk] = *(const v4i*)(ap0 + (size_t)(24 + dk) * 1024);
                n1[dk] = *(const v4i*)(ap1 + (size_t)(24 + dk) * 1024);
            }
        }
        MFMA_STAGE(cb, a0, a1, 4);
        __syncthreads();                   // next stage resident; cb free to reuse
        #pragma unroll
        for (int dk = 0; dk < 4; ++dk) { a0[dk] = n0[dk]; a1[dk] = n1[dk]; }
    }
    MFMA_STAGE(0, a0, a1, 2);              // tail: k0 24..25 in Bs[0]

    // recombine digits (exact integer Horner in fp64) and store both m-tiles
    const int h = nt * 32 + (lane & 31);
    #pragma unroll
    for (int r = 0; r < 16; ++r) {
        int mloc = (r & 3) + 8 * (r >> 2) + 4 * ghalf;
        double s0 = (double)acc0[4][r];
        s0 = s0 * 256.0 + (double)acc0[3][r];
        s0 = s0 * 256.0 + (double)acc0[2][r];
        s0 = s0 * 256.0 + (double)acc0[1][r];
        s0 = s0 * 256.0 + (double)acc0[0][r];
        cur[(size_t)(mt0 * 32 + mloc) * H_SZ + h] = s0 * 0x1p-40;
        double s1 = (double)acc1[4][r];
        s1 = s1 * 256.0 + (double)acc1[3][r];
        s1 = s1 * 256.0 + (double)acc1[2][r];
        s1 = s1 * 256.0 + (double)acc1[1][r];
        s1 = s1 * 256.0 + (double)acc1[0][r];
        cur[(size_t)(mt1 * 32 + mloc) * H_SZ + h] = s1 * 0x1p-40;
    }
}

// ---------------------------------------------------------------------------
// Phase 2 (v2, reverted verbatim — best measured scan, ~88 µs; three
// restructures (v3 barrier-coupled, v4 spin-sync, v5 wave-private+LDS) all
// regressed; this shape is locked):
// 50 LIF steps fp64, block = batch (256 thr = 4 waves). ONE barrier per step:
// ballot masks ping-pong (zmS[2][4]); after the barrier each wave builds a
// PRIVATE padded spike list for the next step in its own LDS slice. List
// entries pre-scaled to row byte offsets; 8 entries read as 2x ds_read_b128.
// ---------------------------------------------------------------------------
__global__ __launch_bounds__(256) void snn_scan(const double* __restrict__ cur,
                                                const float* __restrict__ WrTz,
                                                const float* __restrict__ Wout,
                                                const float* __restrict__ bout,
                                                float* __restrict__ out) {
    const int b    = blockIdx.x;
    const int h    = threadIdx.x;
    const int wv   = h >> 6;
    const int lane = h & 63;

    __shared__ unsigned long long zmS[2][4];
    __shared__ __align__(16) int listS[2][4][264];   // [parity][wave][entry], h<<10
    __shared__ float cntS[H_SZ];

    double v = 0.0, syn = 0.0;
    int cnt = 0;
    int nn[2] = {0, 0};

    const double* curb = cur + (size_t)b * H_SZ + h;
    const char*   wrb  = (const char*)WrTz;          // SGPR-uniform base
    const uint32_t hoff = (uint32_t)(h * 4);
    double inp_c = curb[0];                          // prefetch t=0

    for (int t = 0; t < T_STEPS; ++t) {
        const int p = t & 1;
        const int q = p ^ 1;
        // prefetch next step's input drive (full step of slack)
        int tn = (t < T_STEPS - 1) ? t + 1 : t;
        double inp_n = curb[(size_t)tn * B_SZ * H_SZ];

        // LIF dynamics, reference op order, fp64
        double v_dec = v + 0.05 * ((0.0 - v) + syn);
        double i_dec = 0.9 * syn;
        bool   z_new = v_dec > 0.5;
        v = z_new ? 0.0 : v_dec;
        cnt += z_new ? 1 : 0;

        // gather recurrent drive from this wave's private list (built last step)
        double r0 = 0.0, r1 = 0.0, r2 = 0.0, r3 = 0.0;
        const int* lp = listS[p][wv];
        const int  n  = nn[p];
        for (int j = 0; j < n; j += 8) {
            v4i w0 = *(const v4i*)(lp + j);
            v4i w1 = *(const v4i*)(lp + j + 4);
            float f0 = *(const float*)(wrb + ((uint32_t)w0.x + hoff));
            float f1 = *(const float*)(wrb + ((uint32_t)w0.y + hoff));
            float f2 = *(const float*)(wrb + ((uint32_t)w0.z + hoff));
            float f3 = *(const float*)(wrb + ((uint32_t)w0.w + hoff));
            float f4 = *(const float*)(wrb + ((uint32_t)w1.x + hoff));
            float f5 = *(const float*)(wrb + ((uint32_t)w1.y + hoff));
            float f6 = *(const float*)(wrb + ((uint32_t)w1.z + hoff));
            float f7 = *(const float*)(wrb + ((uint32_t)w1.w + hoff));
            r0 += (double)f0 + (double)f1;
            r1 += (double)f2 + (double)f3;
            r2 += (double)f4 + (double)f5;
            r3 += (double)f6 + (double)f7;
        }

        // publish new spike mask (ping-pong slot q)
        unsigned long long bal = __ballot((int)z_new);
        if (lane == 0) zmS[q][wv] = bal;
        __syncthreads();                             // the ONLY barrier per step

        // build this wave's private next-step list (ascending h, pre-scaled, padded)
        {
            unsigned long long m0 = zmS[q][0], m1 = zmS[q][1],
                               m2 = zmS[q][2], m3 = zmS[q][3];
            int c0 = __popcll(m0), c1 = __popcll(m1),
                c2 = __popcll(m2), c3 = __popcll(m3);
            const int wi = lane >> 4;                // word holding h=4*lane..4*lane+3
            unsigned long long word = zmS[q][wi];
            int basew = (wi > 0 ? c0 : 0) + (wi > 1 ? c1 : 0) + (wi > 2 ? c2 : 0);
            int* lw = listS[q][wv];
            const int hb = 4 * lane;
            #pragma unroll
            for (int u = 0; u < 4; ++u) {
                int bit = (hb + u) & 63;
                bool act = (word >> bit) & 1ull;
                int  pos = __popcll(word & ((1ull << bit) - 1ull));
                if (act) lw[basew + pos] = (hb + u) << 10;
            }
            int tot = c0 + c1 + c2 + c3;
            if (lane < 8) lw[tot + lane] = 256 << 10;   // pad -> zero row of WrTz
            nn[q] = tot;
        }

        syn = (i_dec + inp_c) + ((r0 + r1) + (r2 + r3));
        inp_c = inp_n;
        // no second barrier: private lists are same-wave in-order; zmS slot
        // reuse is separated by the next step's barrier.
    }

    cntS[h] = (float)cnt;
    __syncthreads();
    if (h < L_SZ) {
        double s = 0.0;
        for (int k = 0; k < H_SZ; ++k)
            s += (double)cntS[k] * (double)Wout[(size_t)h * H_SZ + k];
        s += (double)T_STEPS * (double)bout[h];
        out[(size_t)b * L_SZ + h] = (float)(s / (double)T_STEPS);
    }
}

// ---------------------------------------------------------------------------
extern "C" void kernel_launch(void* const* d_in, const int* in_sizes, int n_in,
                              void* d_out, int out_size, void* d_ws, size_t ws_size,
                              hipStream_t stream) {
    const float* x    = (const float*)d_in[0];   // [50,1024,784]
    const float* Wi   = (const float*)d_in[1];   // [256,784]
    const float* Wr   = (const float*)d_in[2];   // [256,256]
    const float* Wout = (const float*)d_in[3];   // [10,256]
    const float* bout = (const float*)d_in[4];   // [10]
    float* out = (float*)d_out;                  // [1024,10]

    // ws layout (~148.8 MB)
    char* ws = (char*)d_ws;
    double*  cur  = (double*)(ws);                       // 104,857,600 B
    float*   WrTz = (float*)(ws + 104857600);            // 257 rows x 256 x 4 = 263,168 B
    uint8_t* SBp  = (uint8_t*)(ws + 105121792);          //   1,064,960 B
    uint8_t* Ap   = (uint8_t*)(ws + 106186752);          //  42,598,400 B

    hipLaunchKernelGGL(transpose_wr, dim3(8, 8), dim3(256), 0, stream, Wr, WrTz);
    hipLaunchKernelGGL(prep_packed, dim3(8, 13), dim3(128), 0, stream, Wi, SBp);
    hipLaunchKernelGGL(pack_x, dim3(M_TOT / 32), dim3(256), 0, stream, x, Ap);
    hipLaunchKernelGGL(gemm_i8s, dim3(M_TOT / 256, 8), dim3(256), 0, stream, Ap, SBp, cur);
    hipLaunchKernelGGL(snn_scan, dim3(B_SZ), dim3(256), 0, stream,
                       cur, WrTz, Wout, bout, out);
}

// Round 7
// 378.157 us; speedup vs baseline: 1.0769x; 1.0098x over previous
//
#include <hip/hip_runtime.h>
#include <cstdint>
#include <cstddef>

#define T_STEPS 50
#define B_SZ    1024
#define N_INP   784
#define H_SZ    256
#define L_SZ    10
#define M_TOT   (T_STEPS * B_SZ)   // 51200
#define NK0     26                 // K padded to 26*32 = 832
#define NSLICE  5                  // 5 balanced base-256 digits of rint(Wi*2^40): exact (|Wi|<0.5)

typedef int v4i  __attribute__((ext_vector_type(4)));
typedef int v16i __attribute__((ext_vector_type(16)));

// ---------------------------------------------------------------------------
// Phase 0a: transpose Wr[h][k] (256x256, fp32) -> WrTz[k][h]; block (0,0) also
// zeroes dummy row 256 (gather pad target).
// ---------------------------------------------------------------------------
__global__ __launch_bounds__(256) void transpose_wr(const float* __restrict__ Wr,
                                                    float* __restrict__ WrTz) {
    __shared__ float tile[32][33];
    int bx = blockIdx.x * 32, by = blockIdx.y * 32;
    int tx = threadIdx.x % 32, ty = threadIdx.x / 32;   // 32 x 8
    #pragma unroll
    for (int j = 0; j < 32; j += 8)
        tile[ty + j][tx] = Wr[(size_t)(by + ty + j) * H_SZ + bx + tx];
    if (blockIdx.x == 0 && blockIdx.y == 0)
        WrTz[(size_t)256 * H_SZ + threadIdx.x] = 0.0f;   // dummy zero row
    __syncthreads();
    #pragma unroll
    for (int j = 0; j < 32; j += 8)
        WrTz[(size_t)(bx + ty + j) * H_SZ + by + tx] = tile[tx][ty + j];
}

// ---------------------------------------------------------------------------
// Phase 0b: Wi -> 5 balanced int8 digits of rint(Wi*2^40), fragment-linear.
// (R5/R6-verified exact, absmax 0.)
// ---------------------------------------------------------------------------
__global__ __launch_bounds__(128) void prep_packed(const float* __restrict__ Wi,
                                                   uint8_t* __restrict__ SBp) {
    const int nt   = blockIdx.x;
    const int k0   = blockIdx.y * 2 + (threadIdx.x >> 6);
    const int lane = threadIdx.x & 63;
    const int h    = nt * 32 + (lane & 31);
    const int g    = k0 * 2 + (lane >> 5);     // 16-float group index

    int wd[NSLICE][4] = {};
    #pragma unroll
    for (int u = 0; u < 16; ++u) {
        double wv = 0.0;
        if (g < 49) wv = (double)Wi[(size_t)h * N_INP + g * 16 + u];
        double r = rint(wv * 0x1p40);
        #pragma unroll
        for (int j = 0; j < NSLICE - 1; ++j) {
            double q  = floor((r + 128.0) * 0.00390625);
            double dj = r - 256.0 * q;                     // in [-128,127]
            wd[j][u >> 2] |= ((int)dj & 0xFF) << ((u & 3) * 8);
            r = q;
        }
        wd[NSLICE - 1][u >> 2] |= ((int)r & 0xFF) << ((u & 3) * 8);
    }
    uint8_t* base = SBp + ((size_t)(nt * NK0 + k0) * NSLICE) * 1024 + lane * 16;
    #pragma unroll
    for (int j = 0; j < NSLICE; ++j)
        *(v4i*)(base + (size_t)j * 1024) = (v4i){wd[j][0], wd[j][1], wd[j][2], wd[j][3]};
}

// ---------------------------------------------------------------------------
// Phase 0c: pack X (binary fp32) -> fragment-linear int8 (R6-verified).
// ---------------------------------------------------------------------------
__global__ __launch_bounds__(256) void pack_x(const float* __restrict__ X,
                                              uint8_t* __restrict__ Ap) {
    const int mt  = blockIdx.x;       // 1600
    const int tid = threadIdx.x;
    #pragma unroll
    for (int i = 0; i < 7; ++i) {
        int s = tid + i * 256;
        if (s < NK0 * 64) {
            int k0 = s >> 6, lane = s & 63;
            int m = mt * 32 + (lane & 31);
            int g = k0 * 2 + (lane >> 5);
            unsigned int bw[4] = {0u, 0u, 0u, 0u};
            if (g < 49) {
                const float* src = X + (size_t)m * N_INP + g * 16;
                #pragma unroll
                for (int q = 0; q < 4; ++q) {
                    float4 f = *(const float4*)(src + q * 4);
                    bw[q] = (f.x != 0.f ? 1u : 0u) | (f.y != 0.f ? 0x100u : 0u)
                          | (f.z != 0.f ? 0x10000u : 0u) | (f.w != 0.f ? 0x1000000u : 0u);
                }
            }
            *(v4i*)(Ap + ((size_t)(mt * NK0 + k0)) * 1024 + lane * 16) =
                (v4i){(int)bw[0], (int)bw[1], (int)bw[2], (int)bw[3]};
        }
    }
}

// ---------------------------------------------------------------------------
// Phase 1 v4: cur = X @ Wi.T exactly via 5 int8-digit MFMAs.
// v2 (R3): B staged via global_load_lds width=16, 4-k0 double-buffered stages.
// v3 (R5): __launch_bounds__(256,2) -> 2 blocks/CU (kept).
// v4 (this round): XCD-aware block swizzle (guide T1). 1-D grid of 1600;
// id = xcd + 8*slot, slot = (x%25)*8 + y  =>  xcd = x/25: the 8 nt-blocks
// sharing one A-panel are adjacent on ONE XCD, so A re-reads (340 MB total)
// and B-digit reads hit the 4 MB per-XCD L2 instead of L3. Pure index remap:
// mt0/mt1/nt values identical, output bit-identical.
// ---------------------------------------------------------------------------
typedef __attribute__((address_space(1))) uint32_t glds_g;
typedef __attribute__((address_space(3))) uint32_t glds_l;

#define STAGE_B(dstbuf, srcp, NI)                                               \
    {                                                                           \
        _Pragma("unroll")                                                       \
        for (int j_ = 0; j_ < (NI); ++j_) {                                     \
            int s_ = j_ * 256 + tid;                                            \
            __builtin_amdgcn_global_load_lds(                                   \
                (glds_g*)((srcp) + (size_t)s_ * 16),                            \
                (glds_l*)((dstbuf) + (size_t)s_ * 16), 16, 0, 0);               \
        }                                                                       \
    }

#define MFMA_STAGE(CB, A0, A1, NK)                                              \
    _Pragma("unroll")                                                           \
    for (int dk = 0; dk < (NK); ++dk) {                                         \
        _Pragma("unroll")                                                       \
        for (int j = 0; j < NSLICE; ++j) {                                      \
            v4i b = *(const v4i*)(Bs[CB] + (dk * NSLICE + j) * 1024 + lane * 16); \
            acc0[j] = __builtin_amdgcn_mfma_i32_32x32x32_i8(A0[dk], b, acc0[j], 0, 0, 0); \
            acc1[j] = __builtin_amdgcn_mfma_i32_32x32x32_i8(A1[dk], b, acc1[j], 0, 0, 0); \
        }                                                                       \
    }

__global__ __launch_bounds__(256, 2) void gemm_i8s(const uint8_t* __restrict__ Ap,
                                                   const uint8_t* __restrict__ SBp,
                                                   double* __restrict__ cur) {
    __shared__ __align__(16) uint8_t Bs[2][4 * NSLICE * 1024];   // 2 x 20 KB

    const int tid   = threadIdx.x;
    const int wave  = tid >> 6;
    const int lane  = tid & 63;
    const int ghalf = lane >> 5;

    // XCD-aware swizzle: id = xcd + 8*slot, slot = (x%25)*8 + y -> xcd = x/25
    const int id   = blockIdx.x;          // 0..1599
    const int xcd  = id & 7;
    const int slot = id >> 3;             // 0..199
    const int x    = xcd * 25 + (slot >> 3);
    const int nt   = slot & 7;

    const int mt0   = (x * 4 + wave) * 2;     // wave owns mt0, mt0+1
    const int mt1   = mt0 + 1;

    const uint8_t* ap0 = Ap + (size_t)mt0 * NK0 * 1024 + lane * 16;
    const uint8_t* ap1 = Ap + (size_t)mt1 * NK0 * 1024 + lane * 16;
    const uint8_t* bbase = SBp + ((size_t)nt * NK0 * NSLICE) * 1024;

    v4i a0[4], a1[4], n0[4], n1[4];

    // prologue: stage stage-0 (k0 0..3), prefetch its A fragments
    STAGE_B(Bs[0], bbase, 5);
    #pragma unroll
    for (int dk = 0; dk < 4; ++dk) {
        a0[dk] = *(const v4i*)(ap0 + (size_t)dk * 1024);
        a1[dk] = *(const v4i*)(ap1 + (size_t)dk * 1024);
    }
    __syncthreads();                       // vmcnt(0): stage-0 resident

    v16i acc0[NSLICE] = {};
    v16i acc1[NSLICE] = {};

    for (int s = 0; s < 6; ++s) {
        const int cb = s & 1;
        if (s < 5) {                       // full next stage: 4 k0, 20 KB
            STAGE_B(Bs[cb ^ 1], bbase + (size_t)(s + 1) * 20480, 5);
            #pragma unroll
            for (int dk = 0; dk < 4; ++dk) {
                n0[dk] = *(const v4i*)(ap0 + (size_t)((s + 1) * 4 + dk) * 1024);
                n1[dk] = *(const v4i*)(ap1 + (size_t)((s + 1) * 4 + dk) * 1024);
            }
        } else {                           // tail stage: k0 24..25 (+pad)
            STAGE_B(Bs[cb ^ 1], bbase + (size_t)6 * 20480, 3);
            #pragma unroll
            for (int dk = 0; dk < 2; ++dk) {
                n0[dk] = *(const v4i*)(ap0 + (size_t)(24 + dk) * 1024);
                n1[dk] = *(const v4i*)(ap1 + (size_t)(24 + dk) * 1024);
            }
        }
        MFMA_STAGE(cb, a0, a1, 4);
        __syncthreads();                   // next stage resident; cb free to reuse
        #pragma unroll
        for (int dk = 0; dk < 4; ++dk) { a0[dk] = n0[dk]; a1[dk] = n1[dk]; }
    }
    MFMA_STAGE(0, a0, a1, 2);              // tail: k0 24..25 in Bs[0]

    // recombine digits (exact integer Horner in fp64) and store both m-tiles
    const int h = nt * 32 + (lane & 31);
    #pragma unroll
    for (int r = 0; r < 16; ++r) {
        int mloc = (r & 3) + 8 * (r >> 2) + 4 * ghalf;
        double s0 = (double)acc0[4][r];
        s0 = s0 * 256.0 + (double)acc0[3][r];
        s0 = s0 * 256.0 + (double)acc0[2][r];
        s0 = s0 * 256.0 + (double)acc0[1][r];
        s0 = s0 * 256.0 + (double)acc0[0][r];
        cur[(size_t)(mt0 * 32 + mloc) * H_SZ + h] = s0 * 0x1p-40;
        double s1 = (double)acc1[4][r];
        s1 = s1 * 256.0 + (double)acc1[3][r];
        s1 = s1 * 256.0 + (double)acc1[2][r];
        s1 = s1 * 256.0 + (double)acc1[1][r];
        s1 = s1 * 256.0 + (double)acc1[0][r];
        cur[(size_t)(mt1 * 32 + mloc) * H_SZ + h] = s1 * 0x1p-40;
    }
}

// ---------------------------------------------------------------------------
// Phase 2 (v2, locked — best measured scan, ~88 µs; three restructures all
// regressed): 50 LIF steps fp64, block = batch (256 thr = 4 waves). ONE
// barrier per step: ballot masks ping-pong; each wave builds a PRIVATE padded
// spike list; entries pre-scaled to row byte offsets; 2x ds_read_b128 per 8.
// ---------------------------------------------------------------------------
__global__ __launch_bounds__(256) void snn_scan(const double* __restrict__ cur,
                                                const float* __restrict__ WrTz,
                                                const float* __restrict__ Wout,
                                                const float* __restrict__ bout,
                                                float* __restrict__ out) {
    const int b    = blockIdx.x;
    const int h    = threadIdx.x;
    const int wv   = h >> 6;
    const int lane = h & 63;

    __shared__ unsigned long long zmS[2][4];
    __shared__ __align__(16) int listS[2][4][264];   // [parity][wave][entry], h<<10
    __shared__ float cntS[H_SZ];

    double v = 0.0, syn = 0.0;
    int cnt = 0;
    int nn[2] = {0, 0};

    const double* curb = cur + (size_t)b * H_SZ + h;
    const char*   wrb  = (const char*)WrTz;          // SGPR-uniform base
    const uint32_t hoff = (uint32_t)(h * 4);
    double inp_c = curb[0];                          // prefetch t=0

    for (int t = 0; t < T_STEPS; ++t) {
        const int p = t & 1;
        const int q = p ^ 1;
        // prefetch next step's input drive (full step of slack)
        int tn = (t < T_STEPS - 1) ? t + 1 : t;
        double inp_n = curb[(size_t)tn * B_SZ * H_SZ];

        // LIF dynamics, reference op order, fp64
        double v_dec = v + 0.05 * ((0.0 - v) + syn);
        double i_dec = 0.9 * syn;
        bool   z_new = v_dec > 0.5;
        v = z_new ? 0.0 : v_dec;
        cnt += z_new ? 1 : 0;

        // gather recurrent drive from this wave's private list (built last step)
        double r0 = 0.0, r1 = 0.0, r2 = 0.0, r3 = 0.0;
        const int* lp = listS[p][wv];
        const int  n  = nn[p];
        for (int j = 0; j < n; j += 8) {
            v4i w0 = *(const v4i*)(lp + j);
            v4i w1 = *(const v4i*)(lp + j + 4);
            float f0 = *(const float*)(wrb + ((uint32_t)w0.x + hoff));
            float f1 = *(const float*)(wrb + ((uint32_t)w0.y + hoff));
            float f2 = *(const float*)(wrb + ((uint32_t)w0.z + hoff));
            float f3 = *(const float*)(wrb + ((uint32_t)w0.w + hoff));
            float f4 = *(const float*)(wrb + ((uint32_t)w1.x + hoff));
            float f5 = *(const float*)(wrb + ((uint32_t)w1.y + hoff));
            float f6 = *(const float*)(wrb + ((uint32_t)w1.z + hoff));
            float f7 = *(const float*)(wrb + ((uint32_t)w1.w + hoff));
            r0 += (double)f0 + (double)f1;
            r1 += (double)f2 + (double)f3;
            r2 += (double)f4 + (double)f5;
            r3 += (double)f6 + (double)f7;
        }

        // publish new spike mask (ping-pong slot q)
        unsigned long long bal = __ballot((int)z_new);
        if (lane == 0) zmS[q][wv] = bal;
        __syncthreads();                             // the ONLY barrier per step

        // build this wave's private next-step list (ascending h, pre-scaled, padded)
        {
            unsigned long long m0 = zmS[q][0], m1 = zmS[q][1],
                               m2 = zmS[q][2], m3 = zmS[q][3];
            int c0 = __popcll(m0), c1 = __popcll(m1),
                c2 = __popcll(m2), c3 = __popcll(m3);
            const int wi = lane >> 4;                // word holding h=4*lane..4*lane+3
            unsigned long long word = zmS[q][wi];
            int basew = (wi > 0 ? c0 : 0) + (wi > 1 ? c1 : 0) + (wi > 2 ? c2 : 0);
            int* lw = listS[q][wv];
            const int hb = 4 * lane;
            #pragma unroll
            for (int u = 0; u < 4; ++u) {
                int bit = (hb + u) & 63;
                bool act = (word >> bit) & 1ull;
                int  pos = __popcll(word & ((1ull << bit) - 1ull));
                if (act) lw[basew + pos] = (hb + u) << 10;
            }
            int tot = c0 + c1 + c2 + c3;
            if (lane < 8) lw[tot + lane] = 256 << 10;   // pad -> zero row of WrTz
            nn[q] = tot;
        }

        syn = (i_dec + inp_c) + ((r0 + r1) + (r2 + r3));
        inp_c = inp_n;
        // no second barrier: private lists are same-wave in-order; zmS slot
        // reuse is separated by the next step's barrier.
    }

    cntS[h] = (float)cnt;
    __syncthreads();
    if (h < L_SZ) {
        double s = 0.0;
        for (int k = 0; k < H_SZ; ++k)
            s += (double)cntS[k] * (double)Wout[(size_t)h * H_SZ + k];
        s += (double)T_STEPS * (double)bout[h];
        out[(size_t)b * L_SZ + h] = (float)(s / (double)T_STEPS);
    }
}

// ---------------------------------------------------------------------------
extern "C" void kernel_launch(void* const* d_in, const int* in_sizes, int n_in,
                              void* d_out, int out_size, void* d_ws, size_t ws_size,
                              hipStream_t stream) {
    const float* x    = (const float*)d_in[0];   // [50,1024,784]
    const float* Wi   = (const float*)d_in[1];   // [256,784]
    const float* Wr   = (const float*)d_in[2];   // [256,256]
    const float* Wout = (const float*)d_in[3];   // [10,256]
    const float* bout = (const float*)d_in[4];   // [10]
    float* out = (float*)d_out;                  // [1024,10]

    // ws layout (~148.8 MB)
    char* ws = (char*)d_ws;
    double*  cur  = (double*)(ws);                       // 104,857,600 B
    float*   WrTz = (float*)(ws + 104857600);            // 257 rows x 256 x 4 = 263,168 B
    uint8_t* SBp  = (uint8_t*)(ws + 105121792);          //   1,064,960 B
    uint8_t* Ap   = (uint8_t*)(ws + 106186752);          //  42,598,400 B

    hipLaunchKernelGGL(transpose_wr, dim3(8, 8), dim3(256), 0, stream, Wr, WrTz);
    hipLaunchKernelGGL(prep_packed, dim3(8, 13), dim3(128), 0, stream, Wi, SBp);
    hipLaunchKernelGGL(pack_x, dim3(M_TOT / 32), dim3(256), 0, stream, x, Ap);
    hipLaunchKernelGGL(gemm_i8s, dim3(1600), dim3(256), 0, stream, Ap, SBp, cur);
    hipLaunchKernelGGL(snn_scan, dim3(B_SZ), dim3(256), 0, stream,
                       cur, WrTz, Wout, bout, out);
}